// Round 11
// baseline (216.597 us; speedup 1.0000x reference)
//
#include <hip/hip_runtime.h>
#include <hip/hip_bf16.h>
#include <math.h>

#define D_MODEL 1024
#define NHEAD 16
#define DHEAD 64
#define SEQ 2048
#define BATCH 2
#define MTOT (BATCH * SEQ)  // 4096

typedef __attribute__((ext_vector_type(8))) short bf16x8;   // 4 VGPRs = MFMA A/B frag
typedef __attribute__((ext_vector_type(4))) float f32x4;    // MFMA C/D frag

static __device__ __forceinline__ ushort f2b(float x) {
  __hip_bfloat16 h = __float2bfloat16(x);
  union { __hip_bfloat16 h; ushort u; } cv; cv.h = h; return cv.u;
}

// async global->LDS, 16B per lane (m97). LDS dest = wave-uniform base + lane*16.
#define GLLDS16(gp, lp)                                                     \
  __builtin_amdgcn_global_load_lds(                                         \
      (const __attribute__((address_space(1))) unsigned int*)(gp),          \
      (__attribute__((address_space(3))) unsigned int*)(lp), 16, 0, 0)

// 0.125 (1/sqrt(Dh)) * log2(e): folded into Q at projection; flash exp2's raw scores
#define QSCALE 0.18033688011112042f

// ---------------------------------------------------------------------------
// prep: fp32->bf16 for X + 4 weights, plus RoPE cos/sin table.
// ---------------------------------------------------------------------------
__global__ __launch_bounds__(256)
void prep(const float* __restrict__ X, const float* __restrict__ Wq,
          const float* __restrict__ Wk, const float* __restrict__ Wv,
          const float* __restrict__ Wo, ushort* __restrict__ Xb,
          ushort* __restrict__ Wqb, ushort* __restrict__ Wkb,
          ushort* __restrict__ Wvb, ushort* __restrict__ Wob,
          float2* __restrict__ tbl) {
  int bid = blockIdx.x;
  if (bid >= 8192) {  // rope table: idx = s*32 + i
    int idx = (bid - 8192) * 256 + threadIdx.x;
    int s = idx >> 5, i = idx & 31;
    float inv = exp2f((float)i * -0.4152410118609203f);  // 10000^(-i/32)
    float sn, cs;
    sincosf((float)s * inv, &sn, &cs);
    tbl[idx] = make_float2(cs, sn);
    return;
  }
  const float* in;
  ushort* out;
  int i;
  if (bid < 4096) {
    in = X; out = Xb; i = bid * 256 + threadIdx.x;
  } else {
    int ws = (bid - 4096) >> 10;
    in = (ws == 0) ? Wq : (ws == 1) ? Wk : (ws == 2) ? Wv : Wo;
    out = (ws == 0) ? Wqb : (ws == 1) ? Wkb : (ws == 2) ? Wvb : Wob;
    i = ((bid - 4096) & 1023) * 256 + threadIdx.x;
  }
  float4 v = ((const float4*)in)[i];
  ushort4 o;
  o.x = f2b(v.x); o.y = f2b(v.y); o.z = f2b(v.z); o.w = f2b(v.w);
  ((ushort4*)out)[i] = o;
}

// ---------------------------------------------------------------------------
// bf16 MFMA GEMM (m97 staging, measured-best R6 config): out = A @ W^T.
// Conflict-free chunk swizzle (R6: SQ_LDS_BANK_CONFLICT=0).
// mode 1 (QKV): RoPE-by-table on Q/K (+QSCALE on Q); V written transposed
// (B,H,Dh,S) with KEY-PERMUTED columns matching flash's S^T C-reg k-slot
// order (verified R10). mode 0: fp32 row-major store (final output).
// ---------------------------------------------------------------------------
__global__ __launch_bounds__(256)
void gemm_bf16(const ushort* __restrict__ A,
               const ushort* __restrict__ W0, const ushort* __restrict__ W1,
               const ushort* __restrict__ W2,
               const float2* __restrict__ tbl,
               float* __restrict__ outF,
               ushort* __restrict__ o0, ushort* __restrict__ o1,
               ushort* __restrict__ o2, int mode) {
  __shared__ ushort As[128 * 32];
  __shared__ ushort Bs[128 * 32];
  const int tid = threadIdx.x;
  const int lane = tid & 63;
  const int w = tid >> 6;
  const int quad = lane >> 4, l15 = lane & 15;
  const int wy = w >> 1, wx = w & 1;
  const int m0 = blockIdx.y * 128, n0 = blockIdx.x * 128;
  const int z = blockIdx.z;
  const ushort* W = (z == 0) ? W0 : (z == 1) ? W1 : W2;
  ushort* outB = (z == 0) ? o0 : (z == 1) ? o1 : o2;

  const int r0 = tid >> 2, c0 = tid & 3;
  const int gc = c0 ^ (((r0 >> 2) ^ r0) & 3);  // f(r0) == f(r0+64)
  const ushort* Ag0 = A + (size_t)(m0 + r0) * D_MODEL + gc * 8;
  const ushort* Ag1 = A + (size_t)(m0 + r0 + 64) * D_MODEL + gc * 8;
  const ushort* Wg0 = W + (size_t)(n0 + r0) * D_MODEL + gc * 8;
  const ushort* Wg1 = W + (size_t)(n0 + r0 + 64) * D_MODEL + gc * 8;

  const int sw = (quad ^ (l15 >> 2) ^ l15) & 3;

  f32x4 acc[4][4];
#pragma unroll
  for (int i = 0; i < 4; ++i)
#pragma unroll
    for (int j = 0; j < 4; ++j) acc[i][j] = (f32x4){0.f, 0.f, 0.f, 0.f};

  for (int kt = 0; kt < D_MODEL / 32; ++kt) {
    if (kt) __syncthreads();
    GLLDS16(Ag0 + kt * 32, &As[(size_t)tid * 8]);
    GLLDS16(Ag1 + kt * 32, &As[(size_t)(tid + 256) * 8]);
    GLLDS16(Wg0 + kt * 32, &Bs[(size_t)tid * 8]);
    GLLDS16(Wg1 + kt * 32, &Bs[(size_t)(tid + 256) * 8]);
    __syncthreads();  // compiler drains vmcnt before barrier

    bf16x8 af[4], bfr[4];
#pragma unroll
    for (int mt = 0; mt < 4; ++mt) {
      int row = wy * 64 + mt * 16 + l15;
      af[mt] = *(const bf16x8*)&As[(row * 4 + sw) * 8];
    }
#pragma unroll
    for (int nt = 0; nt < 4; ++nt) {
      int row = wx * 64 + nt * 16 + l15;
      bfr[nt] = *(const bf16x8*)&Bs[(row * 4 + sw) * 8];
    }
#pragma unroll
    for (int mt = 0; mt < 4; ++mt)
#pragma unroll
      for (int nt = 0; nt < 4; ++nt)
        acc[mt][nt] = __builtin_amdgcn_mfma_f32_16x16x32_bf16(
            af[mt], bfr[nt], acc[mt][nt], 0, 0, 0);
  }

  // ---- epilogue. C/D: row = quad*4+r, col = l15 per 16x16 tile.
  const float qsc = (z == 0) ? QSCALE : 1.0f;
#pragma unroll
  for (int mt = 0; mt < 4; ++mt) {
    int m_base = m0 + wy * 64 + mt * 16 + quad * 4;
    int b = m_base >> 11, s_base = m_base & (SEQ - 1);
#pragma unroll
    for (int nt = 0; nt < 4; ++nt) {
      int n = n0 + wx * 64 + nt * 16 + l15;
      if (mode == 0) {
#pragma unroll
        for (int r = 0; r < 4; ++r)
          outF[(size_t)(m_base + r) * D_MODEL + n] = acc[mt][nt][r];
      } else {
        int h = n >> 6, dh = n & 63;
        if (z == 2) {  // V: transposed + key-permuted columns
          int p_base = (s_base & ~31) | (((s_base >> 2) & 3) << 3) |
                       (((s_base >> 4) & 1) << 2);
          ushort4 o;
          o.x = f2b(acc[mt][nt][0]); o.y = f2b(acc[mt][nt][1]);
          o.z = f2b(acc[mt][nt][2]); o.w = f2b(acc[mt][nt][3]);
          *(ushort4*)&outB[((size_t)(b * NHEAD + h) * DHEAD + dh) * SEQ + p_base] = o;
        } else {       // Q/K: RoPE via table, pair partner via lane shuffle
          int i = nt * 8 + (l15 >> 1);   // freq index, pair-uniform
          bool evn = !(l15 & 1);
#pragma unroll
          for (int r = 0; r < 4; ++r) {
            float v = acc[mt][nt][r];
            float pv = __shfl_xor(v, 1);
            float2 csn = tbl[(s_base + r) * 32 + i];
            v = v * csn.x + (evn ? -pv * csn.y : pv * csn.y);
            v *= qsc;
            outB[(((size_t)(b * NHEAD + h)) * SEQ + s_base + r) * DHEAD + dh] = f2b(v);
          }
        }
      }
    }
  }
}

// ---------------------------------------------------------------------------
// bf16 MFMA causal flash attention v3 -- pipe-split staging.
// S^T operand-swap form (R10, verified): P^T feeds PV straight from regs.
// K frags: DIRECT FROM GLOBAL into registers, double-buffered one tile
// ahead (8 global_load_dwordx4/wave-ktile; 4 waves/block share the tile ->
// L1 absorbs redundancy). V: GLLDS double-buffer, 2x8KB LDS, no staging
// writes on the LDS pipe. ONE barrier per ktile -- its vmcnt(0) drain IS
// the prefetch wait for both the V-DMA and the K register loads.
// LDS pipe/wave-ktile: 8 ds_read_b128 (V frags only; was 16R+4W).
// Manual 2x-unrolled loop (k0/k1 phases) keeps frag buffers in registers.
// __launch_bounds__(256,4) caps VGPR at 128 -> 4 blocks/CU (pairing needs 4
// resident; R7's dbuf loss was 3 blocks at 41.5KB LDS).
// ---------------------------------------------------------------------------
struct KFrags { bf16x8 f[8]; };  // [nt*2 + half]

static __device__ __forceinline__ void load_k(KFrags& kf, const ushort* kbase) {
#pragma unroll
  for (int nt = 0; nt < 4; ++nt) {
    kf.f[nt * 2]     = *(const bf16x8*)(kbase + nt * 1024);
    kf.f[nt * 2 + 1] = *(const bf16x8*)(kbase + nt * 1024 + 32);
  }
}

static __device__ __forceinline__ void compute_tile(
    int kbase0, int qrow, bool diag, const KFrags& kf, const ushort* Vbuf,
    bf16x8 aq0, bf16x8 aq1, int sA, int sB, int l15,
    f32x4* accO, float& rsl) {
  // ---- S^T = K . Q^T : C-tile nt holds keys nt*16+quad*4+r, qrow=l15
  f32x4 sc[4];
#pragma unroll
  for (int nt = 0; nt < 4; ++nt) {
    f32x4 zz = (f32x4){0.f, 0.f, 0.f, 0.f};
    zz = __builtin_amdgcn_mfma_f32_16x16x32_bf16(kf.f[nt * 2], aq0, zz, 0, 0, 0);
    zz = __builtin_amdgcn_mfma_f32_16x16x32_bf16(kf.f[nt * 2 + 1], aq1, zz, 0, 0, 0);
    sc[nt] = zz;
  }
  // ---- exp2 + causal mask + row-sum + pack P^T B-frags in registers
  uint pk[8];
#pragma unroll
  for (int nt = 0; nt < 4; ++nt) {
    int kb = kbase0 + nt * 16;
    ushort us[4];
#pragma unroll
    for (int r = 0; r < 4; ++r) {
      float p = __builtin_amdgcn_exp2f(sc[nt][r]);
      if (diag && kb + r > qrow) p = 0.f;
      rsl += p;
      us[r] = f2b(p);
    }
    pk[nt * 2]     = (uint)us[0] | ((uint)us[1] << 16);
    pk[nt * 2 + 1] = (uint)us[2] | ((uint)us[3] << 16);
  }
  union { uint u[4]; bf16x8 v; } B0, B1;
  B0.u[0] = pk[0]; B0.u[1] = pk[1]; B0.u[2] = pk[2]; B0.u[3] = pk[3];
  B1.u[0] = pk[4]; B1.u[1] = pk[5]; B1.u[2] = pk[6]; B1.u[3] = pk[7];
  // ---- O^T += V^T . P^T  (A from LDS, B straight from registers)
#pragma unroll
  for (int nt = 0; nt < 4; ++nt) {
    const ushort* vr = Vbuf + (nt * 16 + l15) * 64;
    bf16x8 av0 = *(const bf16x8*)(vr + sA);
    bf16x8 av1 = *(const bf16x8*)(vr + sB);
    accO[nt] = __builtin_amdgcn_mfma_f32_16x16x32_bf16(av0, B0.v, accO[nt], 0, 0, 0);
    accO[nt] = __builtin_amdgcn_mfma_f32_16x16x32_bf16(av1, B1.v, accO[nt], 0, 0, 0);
  }
}

__global__ __launch_bounds__(256, 4)
void flash_mfma(const ushort* __restrict__ Q, const ushort* __restrict__ K,
                const ushort* __restrict__ Vt, ushort* __restrict__ O) {
  __shared__ ushort Vs[2][64 * 64];  // [dh][keypos], chunk-swizzled; 16KB
  const int tid = threadIdx.x;
  const int lane = tid & 63, w = tid >> 6;
  const int quad = lane >> 4, l15 = lane & 15;
  const int h = blockIdx.y, b = blockIdx.z;
  const int qt = (h >= 8) ? (31 - blockIdx.x) : blockIdx.x;
  const int bh = b * NHEAD + h;

  // Q as B-operand: lane n=l15=qrow
  const int qrow = qt * 64 + w * 16 + l15;
  const ushort* Qrow = Q + ((size_t)bh * SEQ + qrow) * 64;
  bf16x8 aq0 = *(const bf16x8*)(Qrow + quad * 8);
  bf16x8 aq1 = *(const bf16x8*)(Qrow + 32 + quad * 8);

  // K frag base (direct global): row nt*16+l15 of tile, dh chunk quad*8
  const ushort* Kfb = K + ((size_t)bh * SEQ + l15) * 64 + quad * 8;

  // V staging via GLLDS: thread -> rows rl, rl+32 (dh), slot tid&7, chunk XOR'd
  const int rl = tid >> 3;
  const int gsc = (tid & 7) ^ (rl & 7);
  const ushort* Vg0 = Vt + ((size_t)bh * 64 + rl) * SEQ + gsc * 8;
  const ushort* Vg1 = Vg0 + (size_t)32 * SEQ;

  // V frag reader chunk slots (proven conflict-free geometry, R9)
  const int sA = (quad ^ (l15 & 7)) * 8;
  const int sB = sA ^ 32;

  float rsl = 0.f;
  f32x4 accO[4];
#pragma unroll
  for (int nt = 0; nt < 4; ++nt) accO[nt] = (f32x4){0.f, 0.f, 0.f, 0.f};

  // prologue: V tile 0 -> buf0 (DMA), K tile 0 -> k0 (regs)
  KFrags k0, k1;
  GLLDS16(Vg0, &Vs[0][tid * 8]);
  GLLDS16(Vg1, &Vs[0][2048 + tid * 8]);
  load_k(k0, Kfb);

  int kt = 0;
  while (true) {
    // ---- phase A: compute kt from (k0, buf0); prefetch kt+1 -> (k1, buf1)
    __syncthreads();  // drains V(kt) DMA + K(kt) reg loads; fences buf reuse
    bool more = kt < qt;
    if (more) {
      GLLDS16(Vg0 + (kt + 1) * 64, &Vs[1][tid * 8]);
      GLLDS16(Vg1 + (kt + 1) * 64, &Vs[1][2048 + tid * 8]);
      load_k(k1, Kfb + (size_t)(kt + 1) * 4096);
    }
    compute_tile(kt * 64 + quad * 4, qrow, kt == qt, k0, &Vs[0][0],
                 aq0, aq1, sA, sB, l15, accO, rsl);
    if (!more) break;
    ++kt;
    // ---- phase B: compute kt from (k1, buf1); prefetch kt+1 -> (k0, buf0)
    __syncthreads();
    more = kt < qt;
    if (more) {
      GLLDS16(Vg0 + (kt + 1) * 64, &Vs[0][tid * 8]);
      GLLDS16(Vg1 + (kt + 1) * 64, &Vs[0][2048 + tid * 8]);
      load_k(k0, Kfb + (size_t)(kt + 1) * 4096);
    }
    compute_tile(kt * 64 + quad * 4, qrow, kt == qt, k1, &Vs[1][0],
                 aq0, aq1, sA, sB, l15, accO, rsl);
    if (!more) break;
    ++kt;
  }

  // ---- row-sum reduction across the 4 quads (lane's qrow fixed = l15)
  rsl += __shfl_xor(rsl, 16);
  rsl += __shfl_xor(rsl, 32);
  float invl = 1.f / rsl;

  // ---- epilogue: attn_out bf16, (B,S,H*Dh); lane writes 4 ushort4 runs
  size_t base = ((size_t)(b * SEQ + qrow)) * D_MODEL + h * 64;
#pragma unroll
  for (int nt = 0; nt < 4; ++nt) {
    ushort4 o;
    o.x = f2b(accO[nt][0] * invl);
    o.y = f2b(accO[nt][1] * invl);
    o.z = f2b(accO[nt][2] * invl);
    o.w = f2b(accO[nt][3] * invl);
    *(ushort4*)&O[base + nt * 16 + quad * 4] = o;
  }
}

// ---------------------------------------------------------------------------
extern "C" void kernel_launch(void* const* d_in, const int* in_sizes, int n_in,
                              void* d_out, int out_size, void* d_ws, size_t ws_size,
                              hipStream_t stream) {
  const float* X  = (const float*)d_in[0];
  const float* Wq = (const float*)d_in[1];
  const float* Wk = (const float*)d_in[2];
  const float* Wv = (const float*)d_in[3];
  const float* Wo = (const float*)d_in[4];
  float* out = (float*)d_out;

  ushort* Xb  = (ushort*)d_ws;
  ushort* Wqb = Xb  + (size_t)MTOT * D_MODEL;
  ushort* Wkb = Wqb + (size_t)D_MODEL * D_MODEL;
  ushort* Wvb = Wkb + (size_t)D_MODEL * D_MODEL;
  ushort* Wob = Wvb + (size_t)D_MODEL * D_MODEL;
  ushort* Qw  = Wob + (size_t)D_MODEL * D_MODEL;
  ushort* Kw  = Qw  + (size_t)MTOT * D_MODEL;
  ushort* Vtw = Kw  + (size_t)MTOT * D_MODEL;  // (B,H,Dh,S) key-permuted
  ushort* At  = Vtw + (size_t)MTOT * D_MODEL;
  float2* tbl = (float2*)(At + (size_t)MTOT * D_MODEL);  // 512 KB

  prep<<<8448, 256, 0, stream>>>(X, Wq, Wk, Wv, Wo, Xb, Wqb, Wkb, Wvb, Wob, tbl);

  // QKV projection; RoPE fused (table) on Q/K, Q pre-scaled; V transposed+permuted
  gemm_bf16<<<dim3(D_MODEL / 128, MTOT / 128, 3), 256, 0, stream>>>(
      Xb, Wqb, Wkb, Wvb, tbl, nullptr, Qw, Kw, Vtw, 1);

  flash_mfma<<<dim3(SEQ / 64, NHEAD, BATCH), 256, 0, stream>>>(Qw, Kw, Vtw, At);

  gemm_bf16<<<dim3(D_MODEL / 128, MTOT / 128, 1), 256, 0, stream>>>(
      At, Wob, nullptr, nullptr, tbl, out, nullptr, nullptr, nullptr, 0);
}

// Round 12
// 190.920 us; speedup vs baseline: 1.1345x; 1.1345x over previous
//
#include <hip/hip_runtime.h>
#include <hip/hip_bf16.h>
#include <math.h>

#define D_MODEL 1024
#define NHEAD 16
#define DHEAD 64
#define SEQ 2048
#define BATCH 2
#define MTOT (BATCH * SEQ)  // 4096

typedef __attribute__((ext_vector_type(8))) short bf16x8;   // 4 VGPRs = MFMA A/B frag
typedef __attribute__((ext_vector_type(4))) float f32x4;    // MFMA C/D frag

static __device__ __forceinline__ ushort f2b(float x) {
  __hip_bfloat16 h = __float2bfloat16(x);
  union { __hip_bfloat16 h; ushort u; } cv; cv.h = h; return cv.u;
}

// async global->LDS, 16B per lane (m97). LDS dest = wave-uniform base + lane*16.
#define GLLDS16(gp, lp)                                                     \
  __builtin_amdgcn_global_load_lds(                                         \
      (const __attribute__((address_space(1))) unsigned int*)(gp),          \
      (__attribute__((address_space(3))) unsigned int*)(lp), 16, 0, 0)

// 0.125 (1/sqrt(Dh)) * log2(e): folded into Q at projection; flash exp2's raw scores
#define QSCALE 0.18033688011112042f

// ---------------------------------------------------------------------------
// prep: fp32->bf16 for X + 4 weights, plus RoPE cos/sin table.
// ---------------------------------------------------------------------------
__global__ __launch_bounds__(256)
void prep(const float* __restrict__ X, const float* __restrict__ Wq,
          const float* __restrict__ Wk, const float* __restrict__ Wv,
          const float* __restrict__ Wo, ushort* __restrict__ Xb,
          ushort* __restrict__ Wqb, ushort* __restrict__ Wkb,
          ushort* __restrict__ Wvb, ushort* __restrict__ Wob,
          float2* __restrict__ tbl) {
  int bid = blockIdx.x;
  if (bid >= 8192) {  // rope table: idx = s*32 + i
    int idx = (bid - 8192) * 256 + threadIdx.x;
    int s = idx >> 5, i = idx & 31;
    float inv = exp2f((float)i * -0.4152410118609203f);  // 10000^(-i/32)
    float sn, cs;
    sincosf((float)s * inv, &sn, &cs);
    tbl[idx] = make_float2(cs, sn);
    return;
  }
  const float* in;
  ushort* out;
  int i;
  if (bid < 4096) {
    in = X; out = Xb; i = bid * 256 + threadIdx.x;
  } else {
    int ws = (bid - 4096) >> 10;
    in = (ws == 0) ? Wq : (ws == 1) ? Wk : (ws == 2) ? Wv : Wo;
    out = (ws == 0) ? Wqb : (ws == 1) ? Wkb : (ws == 2) ? Wvb : Wob;
    i = ((bid - 4096) & 1023) * 256 + threadIdx.x;
  }
  float4 v = ((const float4*)in)[i];
  ushort4 o;
  o.x = f2b(v.x); o.y = f2b(v.y); o.z = f2b(v.z); o.w = f2b(v.w);
  ((ushort4*)out)[i] = o;
}

// ---------------------------------------------------------------------------
// bf16 MFMA GEMM (m97 staging, measured-best R6 config): out = A @ W^T.
// Conflict-free chunk swizzle (R6: SQ_LDS_BANK_CONFLICT=0).
// mode 1 (QKV): RoPE-by-table on Q/K (+QSCALE on Q); V written transposed
// (B,H,Dh,S) with KEY-PERMUTED columns matching flash's S^T C-reg k-slot
// order (verified R10). mode 0: fp32 row-major store (final output).
// ---------------------------------------------------------------------------
__global__ __launch_bounds__(256)
void gemm_bf16(const ushort* __restrict__ A,
               const ushort* __restrict__ W0, const ushort* __restrict__ W1,
               const ushort* __restrict__ W2,
               const float2* __restrict__ tbl,
               float* __restrict__ outF,
               ushort* __restrict__ o0, ushort* __restrict__ o1,
               ushort* __restrict__ o2, int mode) {
  __shared__ ushort As[128 * 32];
  __shared__ ushort Bs[128 * 32];
  const int tid = threadIdx.x;
  const int lane = tid & 63;
  const int w = tid >> 6;
  const int quad = lane >> 4, l15 = lane & 15;
  const int wy = w >> 1, wx = w & 1;
  const int m0 = blockIdx.y * 128, n0 = blockIdx.x * 128;
  const int z = blockIdx.z;
  const ushort* W = (z == 0) ? W0 : (z == 1) ? W1 : W2;
  ushort* outB = (z == 0) ? o0 : (z == 1) ? o1 : o2;

  const int r0 = tid >> 2, c0 = tid & 3;
  const int gc = c0 ^ (((r0 >> 2) ^ r0) & 3);  // f(r0) == f(r0+64)
  const ushort* Ag0 = A + (size_t)(m0 + r0) * D_MODEL + gc * 8;
  const ushort* Ag1 = A + (size_t)(m0 + r0 + 64) * D_MODEL + gc * 8;
  const ushort* Wg0 = W + (size_t)(n0 + r0) * D_MODEL + gc * 8;
  const ushort* Wg1 = W + (size_t)(n0 + r0 + 64) * D_MODEL + gc * 8;

  const int sw = (quad ^ (l15 >> 2) ^ l15) & 3;

  f32x4 acc[4][4];
#pragma unroll
  for (int i = 0; i < 4; ++i)
#pragma unroll
    for (int j = 0; j < 4; ++j) acc[i][j] = (f32x4){0.f, 0.f, 0.f, 0.f};

  for (int kt = 0; kt < D_MODEL / 32; ++kt) {
    if (kt) __syncthreads();
    GLLDS16(Ag0 + kt * 32, &As[(size_t)tid * 8]);
    GLLDS16(Ag1 + kt * 32, &As[(size_t)(tid + 256) * 8]);
    GLLDS16(Wg0 + kt * 32, &Bs[(size_t)tid * 8]);
    GLLDS16(Wg1 + kt * 32, &Bs[(size_t)(tid + 256) * 8]);
    __syncthreads();  // compiler drains vmcnt before barrier

    bf16x8 af[4], bfr[4];
#pragma unroll
    for (int mt = 0; mt < 4; ++mt) {
      int row = wy * 64 + mt * 16 + l15;
      af[mt] = *(const bf16x8*)&As[(row * 4 + sw) * 8];
    }
#pragma unroll
    for (int nt = 0; nt < 4; ++nt) {
      int row = wx * 64 + nt * 16 + l15;
      bfr[nt] = *(const bf16x8*)&Bs[(row * 4 + sw) * 8];
    }
#pragma unroll
    for (int mt = 0; mt < 4; ++mt)
#pragma unroll
      for (int nt = 0; nt < 4; ++nt)
        acc[mt][nt] = __builtin_amdgcn_mfma_f32_16x16x32_bf16(
            af[mt], bfr[nt], acc[mt][nt], 0, 0, 0);
  }

  // ---- epilogue. C/D: row = quad*4+r, col = l15 per 16x16 tile.
  const float qsc = (z == 0) ? QSCALE : 1.0f;
#pragma unroll
  for (int mt = 0; mt < 4; ++mt) {
    int m_base = m0 + wy * 64 + mt * 16 + quad * 4;
    int b = m_base >> 11, s_base = m_base & (SEQ - 1);
#pragma unroll
    for (int nt = 0; nt < 4; ++nt) {
      int n = n0 + wx * 64 + nt * 16 + l15;
      if (mode == 0) {
#pragma unroll
        for (int r = 0; r < 4; ++r)
          outF[(size_t)(m_base + r) * D_MODEL + n] = acc[mt][nt][r];
      } else {
        int h = n >> 6, dh = n & 63;
        if (z == 2) {  // V: transposed + key-permuted columns
          int p_base = (s_base & ~31) | (((s_base >> 2) & 3) << 3) |
                       (((s_base >> 4) & 1) << 2);
          ushort4 o;
          o.x = f2b(acc[mt][nt][0]); o.y = f2b(acc[mt][nt][1]);
          o.z = f2b(acc[mt][nt][2]); o.w = f2b(acc[mt][nt][3]);
          *(ushort4*)&outB[((size_t)(b * NHEAD + h) * DHEAD + dh) * SEQ + p_base] = o;
        } else {       // Q/K: RoPE via table, pair partner via lane shuffle
          int i = nt * 8 + (l15 >> 1);   // freq index, pair-uniform
          bool evn = !(l15 & 1);
#pragma unroll
          for (int r = 0; r < 4; ++r) {
            float v = acc[mt][nt][r];
            float pv = __shfl_xor(v, 1);
            float2 csn = tbl[(s_base + r) * 32 + i];
            v = v * csn.x + (evn ? -pv * csn.y : pv * csn.y);
            v *= qsc;
            outB[(((size_t)(b * NHEAD + h)) * SEQ + s_base + r) * DHEAD + dh] = f2b(v);
          }
        }
      }
    }
  }
}

// ---------------------------------------------------------------------------
// bf16 MFMA causal flash attention -- R10 structure (measured best: S^T
// operand-swap, P^T fed to PV from registers, register-prefetch staging,
// unpadded XOR LDS geometry, conflicts=0) + PAIRWISE KTILE STAGING:
// two 64-key tiles staged per round into fixed LDS halves (32KB; grid
// limits us to 4 blocks/CU and LDS still allows 4, so occupancy is
// unchanged -- unlike R7's 41.5KB dbuf) -> ONE barrier pair per TWO ktiles,
// halving the ~400cyc waitcnt drains, and the register prefetch now has two
// tile-computes of slack. NOTE (R11 lesson): K frags must come from LDS --
// struct-wrapped register K-buffers get demoted by the allocator.
// ---------------------------------------------------------------------------
__global__ __launch_bounds__(256)
void flash_mfma(const ushort* __restrict__ Q, const ushort* __restrict__ K,
                const ushort* __restrict__ Vt, ushort* __restrict__ O) {
  __shared__ ushort Ks[2][64 * 64];  // [key][dh], chunk-swizzled; halves=pair
  __shared__ ushort Vs[2][64 * 64];  // [dh][keypos], chunk-swizzled
  const int tid = threadIdx.x;
  const int lane = tid & 63, w = tid >> 6;
  const int quad = lane >> 4, l15 = lane & 15;
  const int h = blockIdx.y, b = blockIdx.z;
  const int qt = (h >= 8) ? (31 - blockIdx.x) : blockIdx.x;
  const int bh = b * NHEAD + h;

  // Q as B-operand (B frag layout == A frag layout): lane n=l15=qrow
  const int qrow = qt * 64 + w * 16 + l15;
  const ushort* Qrow = Q + ((size_t)bh * SEQ + qrow) * 64;
  bf16x8 aq0 = *(const bf16x8*)(Qrow + quad * 8);
  bf16x8 aq1 = *(const bf16x8*)(Qrow + 32 + quad * 8);

  // staging: thread owns rows rl and rl+32, LDS slot tid&7, global chunk XOR'd
  const int rl = tid >> 3;
  const int gsc = (tid & 7) ^ (rl & 7);  // (rl+32)&7 == rl&7
  const ushort* Kg0 = K + ((size_t)bh * SEQ + rl) * 64 + gsc * 8;
  const ushort* Kg1 = Kg0 + (size_t)32 * 64;
  const ushort* Vg0 = Vt + ((size_t)bh * 64 + rl) * SEQ + gsc * 8;
  const ushort* Vg1 = Vg0 + (size_t)32 * SEQ;

  // reader chunk slots (slot quad^(r&7) holds chunk quad; frag rows r&7==l15&7)
  const int sA = (quad ^ (l15 & 7)) * 8;  // dh/keypos 0..31
  const int sB = sA ^ 32;                 // dh/keypos 32..63

  float rsl = 0.f;       // per-lane row sum (lane's qrow)
  f32x4 accO[4];         // O^T dh-tiles: row=dh quad*4+r, col=l15=qrow
#pragma unroll
  for (int nt = 0; nt < 4; ++nt) accO[nt] = (f32x4){0.f, 0.f, 0.f, 0.f};

  // one tile's worth of compute, identical math to R10
  auto do_tile = [&](int kt, const ushort* Kbuf, const ushort* Vbuf) {
    // ---- S^T = K . Q^T : C-tile nt holds keys nt*16+quad*4+r, qrow=l15
    f32x4 sc[4];
#pragma unroll
    for (int nt = 0; nt < 4; ++nt) {
      const ushort* kr = Kbuf + (nt * 16 + l15) * 64;
      bf16x8 bk0 = *(const bf16x8*)(kr + sA);
      bf16x8 bk1 = *(const bf16x8*)(kr + sB);
      f32x4 zz = (f32x4){0.f, 0.f, 0.f, 0.f};
      zz = __builtin_amdgcn_mfma_f32_16x16x32_bf16(bk0, aq0, zz, 0, 0, 0);
      zz = __builtin_amdgcn_mfma_f32_16x16x32_bf16(bk1, aq1, zz, 0, 0, 0);
      sc[nt] = zz;
    }
    // ---- exp2 + causal mask + row-sum + pack P^T B-frags in registers
    const bool diag = (kt == qt);
    uint pk[8];
#pragma unroll
    for (int nt = 0; nt < 4; ++nt) {
      int kb = kt * 64 + nt * 16 + quad * 4;
      ushort us[4];
#pragma unroll
      for (int r = 0; r < 4; ++r) {
        float p = __builtin_amdgcn_exp2f(sc[nt][r]);
        if (diag && kb + r > qrow) p = 0.f;
        rsl += p;
        us[r] = f2b(p);
      }
      pk[nt * 2]     = (uint)us[0] | ((uint)us[1] << 16);
      pk[nt * 2 + 1] = (uint)us[2] | ((uint)us[3] << 16);
    }
    union { uint u[4]; bf16x8 v; } B0, B1;
    B0.u[0] = pk[0]; B0.u[1] = pk[1]; B0.u[2] = pk[2]; B0.u[3] = pk[3];
    B1.u[0] = pk[4]; B1.u[1] = pk[5]; B1.u[2] = pk[6]; B1.u[3] = pk[7];
    // ---- O^T += V^T . P^T  (A from LDS, B straight from registers)
#pragma unroll
    for (int nt = 0; nt < 4; ++nt) {
      const ushort* vr = Vbuf + (nt * 16 + l15) * 64;
      bf16x8 av0 = *(const bf16x8*)(vr + sA);
      bf16x8 av1 = *(const bf16x8*)(vr + sB);
      accO[nt] = __builtin_amdgcn_mfma_f32_16x16x32_bf16(av0, B0.v, accO[nt], 0, 0, 0);
      accO[nt] = __builtin_amdgcn_mfma_f32_16x16x32_bf16(av1, B1.v, accO[nt], 0, 0, 0);
    }
  };

  // prologue: prefetch pair {0, min(1,qt)} into registers
  int t1 = (qt > 0) ? 1 : 0;
  float4 kA0 = *(const float4*)(Kg0);
  float4 kA1 = *(const float4*)(Kg1);
  float4 kB0 = *(const float4*)(Kg0 + (size_t)t1 * 4096);
  float4 kB1 = *(const float4*)(Kg1 + (size_t)t1 * 4096);
  float4 vA0 = *(const float4*)(Vg0);
  float4 vA1 = *(const float4*)(Vg1);
  float4 vB0 = *(const float4*)(Vg0 + t1 * 64);
  float4 vB1 = *(const float4*)(Vg1 + t1 * 64);

  for (int kt0 = 0; kt0 <= qt; kt0 += 2) {
    __syncthreads();  // prior pair's LDS reads complete
    *(float4*)&Ks[0][tid * 8]        = kA0;
    *(float4*)&Ks[0][2048 + tid * 8] = kA1;
    *(float4*)&Ks[1][tid * 8]        = kB0;
    *(float4*)&Ks[1][2048 + tid * 8] = kB1;
    *(float4*)&Vs[0][tid * 8]        = vA0;
    *(float4*)&Vs[0][2048 + tid * 8] = vA1;
    *(float4*)&Vs[1][tid * 8]        = vB0;
    *(float4*)&Vs[1][2048 + tid * 8] = vB1;
    __syncthreads();

    int nk = kt0 + 2;
    if (nk <= qt) {  // prefetch next pair; overlaps TWO tiles of compute
      int nk1 = (nk + 1 <= qt) ? nk + 1 : qt;
      kA0 = *(const float4*)(Kg0 + (size_t)nk * 4096);
      kA1 = *(const float4*)(Kg1 + (size_t)nk * 4096);
      kB0 = *(const float4*)(Kg0 + (size_t)nk1 * 4096);
      kB1 = *(const float4*)(Kg1 + (size_t)nk1 * 4096);
      vA0 = *(const float4*)(Vg0 + nk * 64);
      vA1 = *(const float4*)(Vg1 + nk * 64);
      vB0 = *(const float4*)(Vg0 + nk1 * 64);
      vB1 = *(const float4*)(Vg1 + nk1 * 64);
    }

    do_tile(kt0, &Ks[0][0], &Vs[0][0]);
    if (kt0 + 1 <= qt) do_tile(kt0 + 1, &Ks[1][0], &Vs[1][0]);
  }

  // ---- row-sum reduction across the 4 quads (lane's qrow fixed = l15)
  rsl += __shfl_xor(rsl, 16);
  rsl += __shfl_xor(rsl, 32);
  float invl = 1.f / rsl;

  // ---- epilogue: attn_out bf16, (B,S,H*Dh); lane writes 4 ushort4 runs
  size_t base = ((size_t)(b * SEQ + qrow)) * D_MODEL + h * 64;
#pragma unroll
  for (int nt = 0; nt < 4; ++nt) {
    ushort4 o;
    o.x = f2b(accO[nt][0] * invl);
    o.y = f2b(accO[nt][1] * invl);
    o.z = f2b(accO[nt][2] * invl);
    o.w = f2b(accO[nt][3] * invl);
    *(ushort4*)&O[base + nt * 16 + quad * 4] = o;
  }
}

// ---------------------------------------------------------------------------
extern "C" void kernel_launch(void* const* d_in, const int* in_sizes, int n_in,
                              void* d_out, int out_size, void* d_ws, size_t ws_size,
                              hipStream_t stream) {
  const float* X  = (const float*)d_in[0];
  const float* Wq = (const float*)d_in[1];
  const float* Wk = (const float*)d_in[2];
  const float* Wv = (const float*)d_in[3];
  const float* Wo = (const float*)d_in[4];
  float* out = (float*)d_out;

  ushort* Xb  = (ushort*)d_ws;
  ushort* Wqb = Xb  + (size_t)MTOT * D_MODEL;
  ushort* Wkb = Wqb + (size_t)D_MODEL * D_MODEL;
  ushort* Wvb = Wkb + (size_t)D_MODEL * D_MODEL;
  ushort* Wob = Wvb + (size_t)D_MODEL * D_MODEL;
  ushort* Qw  = Wob + (size_t)D_MODEL * D_MODEL;
  ushort* Kw  = Qw  + (size_t)MTOT * D_MODEL;
  ushort* Vtw = Kw  + (size_t)MTOT * D_MODEL;  // (B,H,Dh,S) key-permuted
  ushort* At  = Vtw + (size_t)MTOT * D_MODEL;
  float2* tbl = (float2*)(At + (size_t)MTOT * D_MODEL);  // 512 KB

  prep<<<8448, 256, 0, stream>>>(X, Wq, Wk, Wv, Wo, Xb, Wqb, Wkb, Wvb, Wob, tbl);

  // QKV projection; RoPE fused (table) on Q/K, Q pre-scaled; V transposed+permuted
  gemm_bf16<<<dim3(D_MODEL / 128, MTOT / 128, 3), 256, 0, stream>>>(
      Xb, Wqb, Wkb, Wvb, tbl, nullptr, Qw, Kw, Vtw, 1);

  flash_mfma<<<dim3(SEQ / 64, NHEAD, BATCH), 256, 0, stream>>>(Qw, Kw, Vtw, At);

  gemm_bf16<<<dim3(D_MODEL / 128, MTOT / 128, 1), 256, 0, stream>>>(
      At, Wob, nullptr, nullptr, tbl, out, nullptr, nullptr, nullptr, 0);
}

// Round 13
// 178.269 us; speedup vs baseline: 1.2150x; 1.0710x over previous
//
#include <hip/hip_runtime.h>
#include <hip/hip_bf16.h>
#include <math.h>

#define D_MODEL 1024
#define NHEAD 16
#define DHEAD 64
#define SEQ 2048
#define BATCH 2
#define MTOT (BATCH * SEQ)  // 4096

typedef __attribute__((ext_vector_type(8))) short bf16x8;   // 4 VGPRs = MFMA A/B frag
typedef __attribute__((ext_vector_type(4))) float f32x4;    // MFMA C/D frag

static __device__ __forceinline__ ushort f2b(float x) {
  __hip_bfloat16 h = __float2bfloat16(x);
  union { __hip_bfloat16 h; ushort u; } cv; cv.h = h; return cv.u;
}

// async global->LDS, 16B per lane (m97). LDS dest = wave-uniform base + lane*16.
#define GLLDS16(gp, lp)                                                     \
  __builtin_amdgcn_global_load_lds(                                         \
      (const __attribute__((address_space(1))) unsigned int*)(gp),          \
      (__attribute__((address_space(3))) unsigned int*)(lp), 16, 0, 0)

// 0.125 (1/sqrt(Dh)) * log2(e): folded into Q at projection; flash exp2's raw scores
#define QSCALE 0.18033688011112042f

// ---------------------------------------------------------------------------
// prep: fp32->bf16 for X + 4 weights, plus RoPE cos/sin table.
// ---------------------------------------------------------------------------
__global__ __launch_bounds__(256)
void prep(const float* __restrict__ X, const float* __restrict__ Wq,
          const float* __restrict__ Wk, const float* __restrict__ Wv,
          const float* __restrict__ Wo, ushort* __restrict__ Xb,
          ushort* __restrict__ Wqb, ushort* __restrict__ Wkb,
          ushort* __restrict__ Wvb, ushort* __restrict__ Wob,
          float2* __restrict__ tbl) {
  int bid = blockIdx.x;
  if (bid >= 8192) {  // rope table: idx = s*32 + i
    int idx = (bid - 8192) * 256 + threadIdx.x;
    int s = idx >> 5, i = idx & 31;
    float inv = exp2f((float)i * -0.4152410118609203f);  // 10000^(-i/32)
    float sn, cs;
    sincosf((float)s * inv, &sn, &cs);
    tbl[idx] = make_float2(cs, sn);
    return;
  }
  const float* in;
  ushort* out;
  int i;
  if (bid < 4096) {
    in = X; out = Xb; i = bid * 256 + threadIdx.x;
  } else {
    int ws = (bid - 4096) >> 10;
    in = (ws == 0) ? Wq : (ws == 1) ? Wk : (ws == 2) ? Wv : Wo;
    out = (ws == 0) ? Wqb : (ws == 1) ? Wkb : (ws == 2) ? Wvb : Wob;
    i = ((bid - 4096) & 1023) * 256 + threadIdx.x;
  }
  float4 v = ((const float4*)in)[i];
  ushort4 o;
  o.x = f2b(v.x); o.y = f2b(v.y); o.z = f2b(v.z); o.w = f2b(v.w);
  ((ushort4*)out)[i] = o;
}

// ---------------------------------------------------------------------------
// bf16 MFMA GEMM (m97 staging, measured-best R6 config): out = A @ W^T.
// Conflict-free chunk swizzle (R6: SQ_LDS_BANK_CONFLICT=0).
// mode 1 (QKV): RoPE-by-table on Q/K (+QSCALE on Q); V written transposed
// (B,H,Dh,S) with KEY-PERMUTED columns matching flash's S^T C-reg k-slot
// order (verified R10). mode 0: fp32 row-major store (final output).
// ---------------------------------------------------------------------------
__global__ __launch_bounds__(256)
void gemm_bf16(const ushort* __restrict__ A,
               const ushort* __restrict__ W0, const ushort* __restrict__ W1,
               const ushort* __restrict__ W2,
               const float2* __restrict__ tbl,
               float* __restrict__ outF,
               ushort* __restrict__ o0, ushort* __restrict__ o1,
               ushort* __restrict__ o2, int mode) {
  __shared__ ushort As[128 * 32];
  __shared__ ushort Bs[128 * 32];
  const int tid = threadIdx.x;
  const int lane = tid & 63;
  const int w = tid >> 6;
  const int quad = lane >> 4, l15 = lane & 15;
  const int wy = w >> 1, wx = w & 1;
  const int m0 = blockIdx.y * 128, n0 = blockIdx.x * 128;
  const int z = blockIdx.z;
  const ushort* W = (z == 0) ? W0 : (z == 1) ? W1 : W2;
  ushort* outB = (z == 0) ? o0 : (z == 1) ? o1 : o2;

  const int r0 = tid >> 2, c0 = tid & 3;
  const int gc = c0 ^ (((r0 >> 2) ^ r0) & 3);  // f(r0) == f(r0+64)
  const ushort* Ag0 = A + (size_t)(m0 + r0) * D_MODEL + gc * 8;
  const ushort* Ag1 = A + (size_t)(m0 + r0 + 64) * D_MODEL + gc * 8;
  const ushort* Wg0 = W + (size_t)(n0 + r0) * D_MODEL + gc * 8;
  const ushort* Wg1 = W + (size_t)(n0 + r0 + 64) * D_MODEL + gc * 8;

  const int sw = (quad ^ (l15 >> 2) ^ l15) & 3;

  f32x4 acc[4][4];
#pragma unroll
  for (int i = 0; i < 4; ++i)
#pragma unroll
    for (int j = 0; j < 4; ++j) acc[i][j] = (f32x4){0.f, 0.f, 0.f, 0.f};

  for (int kt = 0; kt < D_MODEL / 32; ++kt) {
    if (kt) __syncthreads();
    GLLDS16(Ag0 + kt * 32, &As[(size_t)tid * 8]);
    GLLDS16(Ag1 + kt * 32, &As[(size_t)(tid + 256) * 8]);
    GLLDS16(Wg0 + kt * 32, &Bs[(size_t)tid * 8]);
    GLLDS16(Wg1 + kt * 32, &Bs[(size_t)(tid + 256) * 8]);
    __syncthreads();  // compiler drains vmcnt before barrier

    bf16x8 af[4], bfr[4];
#pragma unroll
    for (int mt = 0; mt < 4; ++mt) {
      int row = wy * 64 + mt * 16 + l15;
      af[mt] = *(const bf16x8*)&As[(row * 4 + sw) * 8];
    }
#pragma unroll
    for (int nt = 0; nt < 4; ++nt) {
      int row = wx * 64 + nt * 16 + l15;
      bfr[nt] = *(const bf16x8*)&Bs[(row * 4 + sw) * 8];
    }
#pragma unroll
    for (int mt = 0; mt < 4; ++mt)
#pragma unroll
      for (int nt = 0; nt < 4; ++nt)
        acc[mt][nt] = __builtin_amdgcn_mfma_f32_16x16x32_bf16(
            af[mt], bfr[nt], acc[mt][nt], 0, 0, 0);
  }

  // ---- epilogue. C/D: row = quad*4+r, col = l15 per 16x16 tile.
  const float qsc = (z == 0) ? QSCALE : 1.0f;
#pragma unroll
  for (int mt = 0; mt < 4; ++mt) {
    int m_base = m0 + wy * 64 + mt * 16 + quad * 4;
    int b = m_base >> 11, s_base = m_base & (SEQ - 1);
#pragma unroll
    for (int nt = 0; nt < 4; ++nt) {
      int n = n0 + wx * 64 + nt * 16 + l15;
      if (mode == 0) {
#pragma unroll
        for (int r = 0; r < 4; ++r)
          outF[(size_t)(m_base + r) * D_MODEL + n] = acc[mt][nt][r];
      } else {
        int h = n >> 6, dh = n & 63;
        if (z == 2) {  // V: transposed + key-permuted columns
          int p_base = (s_base & ~31) | (((s_base >> 2) & 3) << 3) |
                       (((s_base >> 4) & 1) << 2);
          ushort4 o;
          o.x = f2b(acc[mt][nt][0]); o.y = f2b(acc[mt][nt][1]);
          o.z = f2b(acc[mt][nt][2]); o.w = f2b(acc[mt][nt][3]);
          *(ushort4*)&outB[((size_t)(b * NHEAD + h) * DHEAD + dh) * SEQ + p_base] = o;
        } else {       // Q/K: RoPE via table, pair partner via lane shuffle
          int i = nt * 8 + (l15 >> 1);   // freq index, pair-uniform
          bool evn = !(l15 & 1);
#pragma unroll
          for (int r = 0; r < 4; ++r) {
            float v = acc[mt][nt][r];
            float pv = __shfl_xor(v, 1);
            float2 csn = tbl[(s_base + r) * 32 + i];
            v = v * csn.x + (evn ? -pv * csn.y : pv * csn.y);
            v *= qsc;
            outB[(((size_t)(b * NHEAD + h)) * SEQ + s_base + r) * DHEAD + dh] = f2b(v);
          }
        }
      }
    }
  }
}

// ---------------------------------------------------------------------------
// bf16 MFMA causal flash attention v4 -- WAVE-SPLIT tiles on the R10 base.
// R10 insight kept: S^T operand-swap, P^T fed to PV from registers,
// register-prefetch staging, unpadded XOR LDS geometry (conflicts=0).
// NEW: wave (i=w&1, j=w>>1) owns keys [i*32,+32) x qrows [j*32,+32).
// In R10 all 4 waves issued IDENTICAL K/V fragment ds_reads (addresses
// depend on l15/quad only) -- the LDS pipe served everything 4x. Split
// halves per-wave frag reads: K 8->4, V 8->4, MFMA count unchanged (8 QK^T
// + 8 PV, PV contracts the wave's full 32 keys; the Vt column permutation
// already matches the 32-key B-frag slot order, verified R10). O partials
// over disjoint key halves are summed once at the end through the reused
// staging LDS. LDS ops/wave-ktile: 20 -> 12.
// ---------------------------------------------------------------------------
__global__ __launch_bounds__(256, 4)
void flash_mfma(const ushort* __restrict__ Q, const ushort* __restrict__ K,
                const ushort* __restrict__ Vt, ushort* __restrict__ O) {
  __shared__ ushort KVs[2 * 64 * 64];  // Ks | Vs; reused as fp32 O-reduction buf
  __shared__ float RSr[2][2][16];      // rowsum partials [j][g][l15]
  ushort* Ks = KVs;
  ushort* Vs = KVs + 4096;
  const int tid = threadIdx.x;
  const int lane = tid & 63, w = tid >> 6;
  const int quad = lane >> 4, l15 = lane & 15;
  const int i = w & 1, j = w >> 1;   // key half / qrow half
  const int h = blockIdx.y, b = blockIdx.z;
  const int qt = (h >= 8) ? (31 - blockIdx.x) : blockIdx.x;
  const int bh = b * NHEAD + h;

  // Q as B-operand, 2 qrow groups g: qrow = qt*64 + j*32 + g*16 + l15
  const int qbase = qt * 64 + j * 32;
  const ushort* Qr0 = Q + ((size_t)bh * SEQ + qbase + l15) * 64;
  const ushort* Qr1 = Qr0 + 16 * 64;
  bf16x8 aq[2][2];
  aq[0][0] = *(const bf16x8*)(Qr0 + quad * 8);
  aq[0][1] = *(const bf16x8*)(Qr0 + 32 + quad * 8);
  aq[1][0] = *(const bf16x8*)(Qr1 + quad * 8);
  aq[1][1] = *(const bf16x8*)(Qr1 + 32 + quad * 8);

  // staging (all 256 threads): rows rl, rl+32; LDS slot tid&7; global chunk XOR'd
  const int rl = tid >> 3;
  const int gsc = (tid & 7) ^ (rl & 7);
  const ushort* Kg0 = K + ((size_t)bh * SEQ + rl) * 64 + gsc * 8;
  const ushort* Kg1 = Kg0 + (size_t)32 * 64;
  const ushort* Vg0 = Vt + ((size_t)bh * 64 + rl) * SEQ + gsc * 8;
  const ushort* Vg1 = Vg0 + (size_t)32 * SEQ;

  // reader chunk slots: slot(c) = c ^ (row&7); frag rows have row&7 == l15&7
  const int x7 = l15 & 7;
  const int sA = (quad ^ x7) * 8;            // K: dh chunk quad
  const int sB = sA ^ 32;                    // K: dh chunk quad+4
  const int sV = ((i * 4 + quad) ^ x7) * 8;  // V: keypos chunk of wave's half

  float rsl[2] = {0.f, 0.f};
  f32x4 accO[4][2];  // [dh tile d][qrow group g]; partial over wave's 32 keys
#pragma unroll
  for (int d = 0; d < 4; ++d)
#pragma unroll
    for (int g = 0; g < 2; ++g) accO[d][g] = (f32x4){0.f, 0.f, 0.f, 0.f};

  float4 pk0 = *(const float4*)(Kg0);
  float4 pk1 = *(const float4*)(Kg1);
  float4 pv0 = *(const float4*)(Vg0);
  float4 pv1 = *(const float4*)(Vg1);

  for (int kt = 0; kt <= qt; ++kt) {
    __syncthreads();  // prior iter's LDS reads complete
    *(float4*)&Ks[tid * 8]        = pk0;
    *(float4*)&Ks[2048 + tid * 8] = pk1;
    *(float4*)&Vs[tid * 8]        = pv0;
    *(float4*)&Vs[2048 + tid * 8] = pv1;
    __syncthreads();
    if (kt < qt) {  // register prefetch of kt+1 overlaps all compute below
      pk0 = *(const float4*)(Kg0 + (size_t)(kt + 1) * 4096);
      pk1 = *(const float4*)(Kg1 + (size_t)(kt + 1) * 4096);
      pv0 = *(const float4*)(Vg0 + (kt + 1) * 64);
      pv1 = *(const float4*)(Vg1 + (kt + 1) * 64);
    }

    // ---- S^T = K . Q^T for wave's 32 keys x 32 qrows (4 ds_read, 8 MFMA)
    f32x4 sc[2][2];  // [key 16-tile mt][qrow group g]
#pragma unroll
    for (int mt = 0; mt < 2; ++mt) {
      const ushort* kr = &Ks[(i * 32 + mt * 16 + l15) * 64];
      bf16x8 bk0 = *(const bf16x8*)(kr + sA);
      bf16x8 bk1 = *(const bf16x8*)(kr + sB);
#pragma unroll
      for (int g = 0; g < 2; ++g) {
        f32x4 zz = (f32x4){0.f, 0.f, 0.f, 0.f};
        zz = __builtin_amdgcn_mfma_f32_16x16x32_bf16(bk0, aq[g][0], zz, 0, 0, 0);
        zz = __builtin_amdgcn_mfma_f32_16x16x32_bf16(bk1, aq[g][1], zz, 0, 0, 0);
        sc[mt][g] = zz;
      }
    }

    // ---- exp2 + causal mask + row-sums + pack P^T B-frags (32 keys) in regs
    const bool diag = (kt == qt);
    uint pb[2][4];  // [g][uint slot]
#pragma unroll
    for (int mt = 0; mt < 2; ++mt) {
      int kb = kt * 64 + i * 32 + mt * 16 + quad * 4;
#pragma unroll
      for (int g = 0; g < 2; ++g) {
        int qr = qbase + g * 16 + l15;
        ushort us[4];
#pragma unroll
        for (int r = 0; r < 4; ++r) {
          float p = __builtin_amdgcn_exp2f(sc[mt][g][r]);
          if (diag && kb + r > qr) p = 0.f;
          rsl[g] += p;
          us[r] = f2b(p);
        }
        pb[g][mt * 2]     = (uint)us[0] | ((uint)us[1] << 16);
        pb[g][mt * 2 + 1] = (uint)us[2] | ((uint)us[3] << 16);
      }
    }
    union { uint u[4]; bf16x8 v; } P0, P1;
    P0.u[0] = pb[0][0]; P0.u[1] = pb[0][1]; P0.u[2] = pb[0][2]; P0.u[3] = pb[0][3];
    P1.u[0] = pb[1][0]; P1.u[1] = pb[1][1]; P1.u[2] = pb[1][2]; P1.u[3] = pb[1][3];

    // ---- O^T += V^T . P^T over wave's 32 keys (4 ds_read, 8 MFMA)
#pragma unroll
    for (int d = 0; d < 4; ++d) {
      bf16x8 av = *(const bf16x8*)&Vs[(d * 16 + l15) * 64 + sV];
      accO[d][0] = __builtin_amdgcn_mfma_f32_16x16x32_bf16(av, P0.v, accO[d][0], 0, 0, 0);
      accO[d][1] = __builtin_amdgcn_mfma_f32_16x16x32_bf16(av, P1.v, accO[d][1], 0, 0, 0);
    }
  }

  // ---- reduce row sums across quads (qrow fixed = (g,l15) per lane)
#pragma unroll
  for (int g = 0; g < 2; ++g) {
    rsl[g] += __shfl_xor(rsl[g], 16);
    rsl[g] += __shfl_xor(rsl[g], 32);
  }

  // ---- cross-wave O reduction: i=1 partials added into i=0 via reused LDS
  __syncthreads();  // all compute reads of Ks/Vs done; safe to alias
  float4* Red = (float4*)KVs;  // 16 KB = 2 (j) x 8 (d,g) x 64 lanes x float4
  if (i == 1) {
#pragma unroll
    for (int d = 0; d < 4; ++d)
#pragma unroll
      for (int g = 0; g < 2; ++g)
        Red[(size_t)j * 512 + (d * 2 + g) * 64 + lane] =
            (float4){accO[d][g][0], accO[d][g][1], accO[d][g][2], accO[d][g][3]};
    if (quad == 0) { RSr[j][0][l15] = rsl[0]; RSr[j][1][l15] = rsl[1]; }
  }
  __syncthreads();
  if (i == 0) {
    float invl[2];
#pragma unroll
    for (int g = 0; g < 2; ++g) invl[g] = 1.f / (rsl[g] + RSr[j][g][l15]);
#pragma unroll
    for (int d = 0; d < 4; ++d) {
#pragma unroll
      for (int g = 0; g < 2; ++g) {
        float4 o = Red[(size_t)j * 512 + (d * 2 + g) * 64 + lane];
        int qrow = qbase + g * 16 + l15;
        size_t base = ((size_t)(b * SEQ + qrow)) * D_MODEL + h * 64 + d * 16 + quad * 4;
        ushort4 s;
        s.x = f2b((accO[d][g][0] + o.x) * invl[g]);
        s.y = f2b((accO[d][g][1] + o.y) * invl[g]);
        s.z = f2b((accO[d][g][2] + o.z) * invl[g]);
        s.w = f2b((accO[d][g][3] + o.w) * invl[g]);
        *(ushort4*)&O[base] = s;
      }
    }
  }
}

// ---------------------------------------------------------------------------
extern "C" void kernel_launch(void* const* d_in, const int* in_sizes, int n_in,
                              void* d_out, int out_size, void* d_ws, size_t ws_size,
                              hipStream_t stream) {
  const float* X  = (const float*)d_in[0];
  const float* Wq = (const float*)d_in[1];
  const float* Wk = (const float*)d_in[2];
  const float* Wv = (const float*)d_in[3];
  const float* Wo = (const float*)d_in[4];
  float* out = (float*)d_out;

  ushort* Xb  = (ushort*)d_ws;
  ushort* Wqb = Xb  + (size_t)MTOT * D_MODEL;
  ushort* Wkb = Wqb + (size_t)D_MODEL * D_MODEL;
  ushort* Wvb = Wkb + (size_t)D_MODEL * D_MODEL;
  ushort* Wob = Wvb + (size_t)D_MODEL * D_MODEL;
  ushort* Qw  = Wob + (size_t)D_MODEL * D_MODEL;
  ushort* Kw  = Qw  + (size_t)MTOT * D_MODEL;
  ushort* Vtw = Kw  + (size_t)MTOT * D_MODEL;  // (B,H,Dh,S) key-permuted
  ushort* At  = Vtw + (size_t)MTOT * D_MODEL;
  float2* tbl = (float2*)(At + (size_t)MTOT * D_MODEL);  // 512 KB

  prep<<<8448, 256, 0, stream>>>(X, Wq, Wk, Wv, Wo, Xb, Wqb, Wkb, Wvb, Wob, tbl);

  // QKV projection; RoPE fused (table) on Q/K, Q pre-scaled; V transposed+permuted
  gemm_bf16<<<dim3(D_MODEL / 128, MTOT / 128, 3), 256, 0, stream>>>(
      Xb, Wqb, Wkb, Wvb, tbl, nullptr, Qw, Kw, Vtw, 1);

  flash_mfma<<<dim3(SEQ / 64, NHEAD, BATCH), 256, 0, stream>>>(Qw, Kw, Vtw, At);

  gemm_bf16<<<dim3(D_MODEL / 128, MTOT / 128, 1), 256, 0, stream>>>(
      At, Wob, nullptr, nullptr, tbl, out, nullptr, nullptr, nullptr, 0);
}

// Round 14
// 176.930 us; speedup vs baseline: 1.2242x; 1.0076x over previous
//
#include <hip/hip_runtime.h>
#include <hip/hip_bf16.h>
#include <math.h>

#define D_MODEL 1024
#define NHEAD 16
#define DHEAD 64
#define SEQ 2048
#define BATCH 2
#define MTOT (BATCH * SEQ)  // 4096

typedef __attribute__((ext_vector_type(8))) short bf16x8;   // 4 VGPRs = MFMA A/B frag
typedef __attribute__((ext_vector_type(4))) float f32x4;    // MFMA C/D frag

static __device__ __forceinline__ ushort f2b(float x) {
  __hip_bfloat16 h = __float2bfloat16(x);
  union { __hip_bfloat16 h; ushort u; } cv; cv.h = h; return cv.u;
}

// async global->LDS, 16B per lane (m97). LDS dest = wave-uniform base + lane*16.
#define GLLDS16(gp, lp)                                                     \
  __builtin_amdgcn_global_load_lds(                                         \
      (const __attribute__((address_space(1))) unsigned int*)(gp),          \
      (__attribute__((address_space(3))) unsigned int*)(lp), 16, 0, 0)

// 0.125 (1/sqrt(Dh)) * log2(e): folded into Q at projection; flash exp2's raw scores
#define QSCALE 0.18033688011112042f

// ---------------------------------------------------------------------------
// prep: fp32->bf16 for X + 4 weights, plus RoPE cos/sin table.
// ---------------------------------------------------------------------------
__global__ __launch_bounds__(256)
void prep(const float* __restrict__ X, const float* __restrict__ Wq,
          const float* __restrict__ Wk, const float* __restrict__ Wv,
          const float* __restrict__ Wo, ushort* __restrict__ Xb,
          ushort* __restrict__ Wqb, ushort* __restrict__ Wkb,
          ushort* __restrict__ Wvb, ushort* __restrict__ Wob,
          float2* __restrict__ tbl) {
  int bid = blockIdx.x;
  if (bid >= 8192) {  // rope table: idx = s*32 + i
    int idx = (bid - 8192) * 256 + threadIdx.x;
    int s = idx >> 5, i = idx & 31;
    float inv = exp2f((float)i * -0.4152410118609203f);  // 10000^(-i/32)
    float sn, cs;
    sincosf((float)s * inv, &sn, &cs);
    tbl[idx] = make_float2(cs, sn);
    return;
  }
  const float* in;
  ushort* out;
  int i;
  if (bid < 4096) {
    in = X; out = Xb; i = bid * 256 + threadIdx.x;
  } else {
    int ws = (bid - 4096) >> 10;
    in = (ws == 0) ? Wq : (ws == 1) ? Wk : (ws == 2) ? Wv : Wo;
    out = (ws == 0) ? Wqb : (ws == 1) ? Wkb : (ws == 2) ? Wvb : Wob;
    i = ((bid - 4096) & 1023) * 256 + threadIdx.x;
  }
  float4 v = ((const float4*)in)[i];
  ushort4 o;
  o.x = f2b(v.x); o.y = f2b(v.y); o.z = f2b(v.z); o.w = f2b(v.w);
  ((ushort4*)out)[i] = o;
}

// ---------------------------------------------------------------------------
// bf16 MFMA GEMM (m97 staging, measured-best R6 config): out = A @ W^T.
// Conflict-free chunk swizzle (R6: SQ_LDS_BANK_CONFLICT=0).
// mode 1 (QKV): RoPE-by-table on Q/K (+QSCALE on Q); V written transposed
// (B,H,Dh,S) with KEY-PERMUTED columns matching flash's S^T C-reg k-slot
// order (verified R10). mode 0: fp32 row-major store (final output).
// ---------------------------------------------------------------------------
__global__ __launch_bounds__(256)
void gemm_bf16(const ushort* __restrict__ A,
               const ushort* __restrict__ W0, const ushort* __restrict__ W1,
               const ushort* __restrict__ W2,
               const float2* __restrict__ tbl,
               float* __restrict__ outF,
               ushort* __restrict__ o0, ushort* __restrict__ o1,
               ushort* __restrict__ o2, int mode) {
  __shared__ ushort As[128 * 32];
  __shared__ ushort Bs[128 * 32];
  const int tid = threadIdx.x;
  const int lane = tid & 63;
  const int w = tid >> 6;
  const int quad = lane >> 4, l15 = lane & 15;
  const int wy = w >> 1, wx = w & 1;
  const int m0 = blockIdx.y * 128, n0 = blockIdx.x * 128;
  const int z = blockIdx.z;
  const ushort* W = (z == 0) ? W0 : (z == 1) ? W1 : W2;
  ushort* outB = (z == 0) ? o0 : (z == 1) ? o1 : o2;

  const int r0 = tid >> 2, c0 = tid & 3;
  const int gc = c0 ^ (((r0 >> 2) ^ r0) & 3);  // f(r0) == f(r0+64)
  const ushort* Ag0 = A + (size_t)(m0 + r0) * D_MODEL + gc * 8;
  const ushort* Ag1 = A + (size_t)(m0 + r0 + 64) * D_MODEL + gc * 8;
  const ushort* Wg0 = W + (size_t)(n0 + r0) * D_MODEL + gc * 8;
  const ushort* Wg1 = W + (size_t)(n0 + r0 + 64) * D_MODEL + gc * 8;

  const int sw = (quad ^ (l15 >> 2) ^ l15) & 3;

  f32x4 acc[4][4];
#pragma unroll
  for (int i = 0; i < 4; ++i)
#pragma unroll
    for (int j = 0; j < 4; ++j) acc[i][j] = (f32x4){0.f, 0.f, 0.f, 0.f};

  for (int kt = 0; kt < D_MODEL / 32; ++kt) {
    if (kt) __syncthreads();
    GLLDS16(Ag0 + kt * 32, &As[(size_t)tid * 8]);
    GLLDS16(Ag1 + kt * 32, &As[(size_t)(tid + 256) * 8]);
    GLLDS16(Wg0 + kt * 32, &Bs[(size_t)tid * 8]);
    GLLDS16(Wg1 + kt * 32, &Bs[(size_t)(tid + 256) * 8]);
    __syncthreads();  // compiler drains vmcnt before barrier

    bf16x8 af[4], bfr[4];
#pragma unroll
    for (int mt = 0; mt < 4; ++mt) {
      int row = wy * 64 + mt * 16 + l15;
      af[mt] = *(const bf16x8*)&As[(row * 4 + sw) * 8];
    }
#pragma unroll
    for (int nt = 0; nt < 4; ++nt) {
      int row = wx * 64 + nt * 16 + l15;
      bfr[nt] = *(const bf16x8*)&Bs[(row * 4 + sw) * 8];
    }
#pragma unroll
    for (int mt = 0; mt < 4; ++mt)
#pragma unroll
      for (int nt = 0; nt < 4; ++nt)
        acc[mt][nt] = __builtin_amdgcn_mfma_f32_16x16x32_bf16(
            af[mt], bfr[nt], acc[mt][nt], 0, 0, 0);
  }

  // ---- epilogue. C/D: row = quad*4+r, col = l15 per 16x16 tile.
  const float qsc = (z == 0) ? QSCALE : 1.0f;
#pragma unroll
  for (int mt = 0; mt < 4; ++mt) {
    int m_base = m0 + wy * 64 + mt * 16 + quad * 4;
    int b = m_base >> 11, s_base = m_base & (SEQ - 1);
#pragma unroll
    for (int nt = 0; nt < 4; ++nt) {
      int n = n0 + wx * 64 + nt * 16 + l15;
      if (mode == 0) {
#pragma unroll
        for (int r = 0; r < 4; ++r)
          outF[(size_t)(m_base + r) * D_MODEL + n] = acc[mt][nt][r];
      } else {
        int h = n >> 6, dh = n & 63;
        if (z == 2) {  // V: transposed + key-permuted columns
          int p_base = (s_base & ~31) | (((s_base >> 2) & 3) << 3) |
                       (((s_base >> 4) & 1) << 2);
          ushort4 o;
          o.x = f2b(acc[mt][nt][0]); o.y = f2b(acc[mt][nt][1]);
          o.z = f2b(acc[mt][nt][2]); o.w = f2b(acc[mt][nt][3]);
          *(ushort4*)&outB[((size_t)(b * NHEAD + h) * DHEAD + dh) * SEQ + p_base] = o;
        } else {       // Q/K: RoPE via table, pair partner via lane shuffle
          int i = nt * 8 + (l15 >> 1);   // freq index, pair-uniform
          bool evn = !(l15 & 1);
#pragma unroll
          for (int r = 0; r < 4; ++r) {
            float v = acc[mt][nt][r];
            float pv = __shfl_xor(v, 1);
            float2 csn = tbl[(s_base + r) * 32 + i];
            v = v * csn.x + (evn ? -pv * csn.y : pv * csn.y);
            v *= qsc;
            outB[(((size_t)(b * NHEAD + h)) * SEQ + s_base + r) * DHEAD + dh] = f2b(v);
          }
        }
      }
    }
  }
}

// ---------------------------------------------------------------------------
// bf16 MFMA causal flash attention -- R10 measured-best configuration.
// S^T operand-swap form: S^T = K.Q^T via mfma(A=K, B=Q); C-layout puts qrow
// in l15, keys in quad*4+r == B-operand orientation for O^T = V^T.P^T, so
// exp2'd probabilities feed the PV MFMA straight from registers (no P LDS
// round-trip). Vt columns key-permuted at projection to match C-reg k-slot
// order (verified R10). Register-prefetch staging (cross-tile latency
// overlap, no extra LDS); unpadded XOR chunk geometry (conflicts=0, R9).
// Per-lane row sums, 2 shuffles at the end. Heads 8-15 reversed for balance.
// Plateau note: R7/R11/R12/R13 structural variants (GLLDS dbuf, K-in-regs,
// pairwise staging, wave-split) all landed neutral or worse.
// ---------------------------------------------------------------------------
__global__ __launch_bounds__(256)
void flash_mfma(const ushort* __restrict__ Q, const ushort* __restrict__ K,
                const ushort* __restrict__ Vt, ushort* __restrict__ O) {
  __shared__ ushort Ks[64 * 64];     // [key][dh], chunk-swizzled
  __shared__ ushort Vs[64 * 64];     // [dh][keypos], chunk-swizzled
  const int tid = threadIdx.x;
  const int lane = tid & 63, w = tid >> 6;
  const int quad = lane >> 4, l15 = lane & 15;
  const int h = blockIdx.y, b = blockIdx.z;
  const int qt = (h >= 8) ? (31 - blockIdx.x) : blockIdx.x;
  const int bh = b * NHEAD + h;

  // Q as B-operand (B frag layout == A frag layout): lane n=l15=qrow
  const int qrow = qt * 64 + w * 16 + l15;
  const ushort* Qrow = Q + ((size_t)bh * SEQ + qrow) * 64;
  bf16x8 aq0 = *(const bf16x8*)(Qrow + quad * 8);
  bf16x8 aq1 = *(const bf16x8*)(Qrow + 32 + quad * 8);

  // staging: thread owns rows rl and rl+32, LDS slot tid&7, global chunk XOR'd
  const int rl = tid >> 3;
  const int gsc = (tid & 7) ^ (rl & 7);  // (rl+32)&7 == rl&7
  const ushort* Kg0 = K + ((size_t)bh * SEQ + rl) * 64 + gsc * 8;
  const ushort* Kg1 = Kg0 + (size_t)32 * 64;
  const ushort* Vg0 = Vt + ((size_t)bh * 64 + rl) * SEQ + gsc * 8;
  const ushort* Vg1 = Vg0 + (size_t)32 * SEQ;

  // reader chunk slots (slot quad^(r&7) holds chunk quad; frag rows r&7==l15&7)
  const int sA = (quad ^ (l15 & 7)) * 8;  // dh/keypos 0..31
  const int sB = sA ^ 32;                 // dh/keypos 32..63 (chunk quad+4)

  float rsl = 0.f;       // per-lane row sum (lane's qrow)
  f32x4 accO[4];         // O^T dh-tiles: row=dh quad*4+r, col=l15=qrow
#pragma unroll
  for (int nt = 0; nt < 4; ++nt) accO[nt] = (f32x4){0.f, 0.f, 0.f, 0.f};

  float4 pk0 = *(const float4*)(Kg0);
  float4 pk1 = *(const float4*)(Kg1);
  float4 pv0 = *(const float4*)(Vg0);
  float4 pv1 = *(const float4*)(Vg1);

  for (int kt = 0; kt <= qt; ++kt) {
    __syncthreads();  // prior iter's LDS reads complete
    *(float4*)&Ks[tid * 8]        = pk0;
    *(float4*)&Ks[2048 + tid * 8] = pk1;
    *(float4*)&Vs[tid * 8]        = pv0;
    *(float4*)&Vs[2048 + tid * 8] = pv1;
    __syncthreads();
    if (kt < qt) {  // prefetch kt+1 into registers; overlaps all compute below
      pk0 = *(const float4*)(Kg0 + (size_t)(kt + 1) * 64 * 64);
      pk1 = *(const float4*)(Kg1 + (size_t)(kt + 1) * 64 * 64);
      pv0 = *(const float4*)(Vg0 + (kt + 1) * 64);
      pv1 = *(const float4*)(Vg1 + (kt + 1) * 64);
    }

    // ---- S^T = K . Q^T : C-tile nt holds keys nt*16+quad*4+r, qrow=l15
    f32x4 sc[4];
#pragma unroll
    for (int nt = 0; nt < 4; ++nt) {
      const ushort* kr = &Ks[(nt * 16 + l15) * 64];
      bf16x8 bk0 = *(const bf16x8*)(kr + sA);
      bf16x8 bk1 = *(const bf16x8*)(kr + sB);
      f32x4 zz = (f32x4){0.f, 0.f, 0.f, 0.f};
      zz = __builtin_amdgcn_mfma_f32_16x16x32_bf16(bk0, aq0, zz, 0, 0, 0);
      zz = __builtin_amdgcn_mfma_f32_16x16x32_bf16(bk1, aq1, zz, 0, 0, 0);
      sc[nt] = zz;
    }

    // ---- exp2 + causal mask + row-sum + pack P^T B-frags in registers
    const bool diag = (kt == qt);
    uint pk[8];
#pragma unroll
    for (int nt = 0; nt < 4; ++nt) {
      int kbase = kt * 64 + nt * 16 + quad * 4;
      ushort us[4];
#pragma unroll
      for (int r = 0; r < 4; ++r) {
        float p = __builtin_amdgcn_exp2f(sc[nt][r]);
        if (diag && kbase + r > qrow) p = 0.f;
        rsl += p;
        us[r] = f2b(p);
      }
      pk[nt * 2]     = (uint)us[0] | ((uint)us[1] << 16);
      pk[nt * 2 + 1] = (uint)us[2] | ((uint)us[3] << 16);
    }
    union { uint u[4]; bf16x8 v; } B0, B1;
    B0.u[0] = pk[0]; B0.u[1] = pk[1]; B0.u[2] = pk[2]; B0.u[3] = pk[3];
    B1.u[0] = pk[4]; B1.u[1] = pk[5]; B1.u[2] = pk[6]; B1.u[3] = pk[7];

    // ---- O^T += V^T . P^T  (A from LDS, B straight from registers)
#pragma unroll
    for (int nt = 0; nt < 4; ++nt) {
      const ushort* vr = &Vs[(nt * 16 + l15) * 64];
      bf16x8 av0 = *(const bf16x8*)(vr + sA);
      bf16x8 av1 = *(const bf16x8*)(vr + sB);
      accO[nt] = __builtin_amdgcn_mfma_f32_16x16x32_bf16(av0, B0.v, accO[nt], 0, 0, 0);
      accO[nt] = __builtin_amdgcn_mfma_f32_16x16x32_bf16(av1, B1.v, accO[nt], 0, 0, 0);
    }
  }

  // ---- row-sum reduction across the 4 quads (lane's qrow fixed = l15)
  rsl += __shfl_xor(rsl, 16);
  rsl += __shfl_xor(rsl, 32);
  float invl = 1.f / rsl;

  // ---- epilogue: attn_out bf16, (B,S,H*Dh); lane writes 4 ushort4 runs
  size_t base = ((size_t)(b * SEQ + qrow)) * D_MODEL + h * 64;
#pragma unroll
  for (int nt = 0; nt < 4; ++nt) {
    ushort4 o;
    o.x = f2b(accO[nt][0] * invl);
    o.y = f2b(accO[nt][1] * invl);
    o.z = f2b(accO[nt][2] * invl);
    o.w = f2b(accO[nt][3] * invl);
    *(ushort4*)&O[base + nt * 16 + quad * 4] = o;
  }
}

// ---------------------------------------------------------------------------
extern "C" void kernel_launch(void* const* d_in, const int* in_sizes, int n_in,
                              void* d_out, int out_size, void* d_ws, size_t ws_size,
                              hipStream_t stream) {
  const float* X  = (const float*)d_in[0];
  const float* Wq = (const float*)d_in[1];
  const float* Wk = (const float*)d_in[2];
  const float* Wv = (const float*)d_in[3];
  const float* Wo = (const float*)d_in[4];
  float* out = (float*)d_out;

  ushort* Xb  = (ushort*)d_ws;
  ushort* Wqb = Xb  + (size_t)MTOT * D_MODEL;
  ushort* Wkb = Wqb + (size_t)D_MODEL * D_MODEL;
  ushort* Wvb = Wkb + (size_t)D_MODEL * D_MODEL;
  ushort* Wob = Wvb + (size_t)D_MODEL * D_MODEL;
  ushort* Qw  = Wob + (size_t)D_MODEL * D_MODEL;
  ushort* Kw  = Qw  + (size_t)MTOT * D_MODEL;
  ushort* Vtw = Kw  + (size_t)MTOT * D_MODEL;  // (B,H,Dh,S) key-permuted
  ushort* At  = Vtw + (size_t)MTOT * D_MODEL;
  float2* tbl = (float2*)(At + (size_t)MTOT * D_MODEL);  // 512 KB

  prep<<<8448, 256, 0, stream>>>(X, Wq, Wk, Wv, Wo, Xb, Wqb, Wkb, Wvb, Wob, tbl);

  // QKV projection; RoPE fused (table) on Q/K, Q pre-scaled; V transposed+permuted
  gemm_bf16<<<dim3(D_MODEL / 128, MTOT / 128, 3), 256, 0, stream>>>(
      Xb, Wqb, Wkb, Wvb, tbl, nullptr, Qw, Kw, Vtw, 1);

  flash_mfma<<<dim3(SEQ / 64, NHEAD, BATCH), 256, 0, stream>>>(Qw, Kw, Vtw, At);

  gemm_bf16<<<dim3(D_MODEL / 128, MTOT / 128, 1), 256, 0, stream>>>(
      At, Wob, nullptr, nullptr, tbl, out, nullptr, nullptr, nullptr, 0);
}